// Round 9
// baseline (173.521 us; speedup 1.0000x reference)
//
#include <hip/hip_runtime.h>

#define BATCH   16384
#define HIDDEN  1024
#define K2      2048     // x | h_prev   (h_mem folded into MQ gather)
#define MEMSZ   1024
#define NBITS   10

#define BM 256
#define BN 256
#define BK 64
#define NT (K2 / BK)     // 32 K-tiles

typedef __bf16 bf16x8 __attribute__((ext_vector_type(8)));
typedef float  f32x4  __attribute__((ext_vector_type(4)));
typedef unsigned short u16x8 __attribute__((ext_vector_type(8)));

__device__ __forceinline__ unsigned short f2bf(float f) {
    unsigned int u = __float_as_uint(f);
    u += 0x7FFFu + ((u >> 16) & 1u);   // round-to-nearest-even
    return (unsigned short)(u >> 16);
}

__device__ __forceinline__ u16x8 f2bf8(float4 a, float4 b) {
    u16x8 r;
    r[0] = f2bf(a.x); r[1] = f2bf(a.y); r[2] = f2bf(a.z); r[3] = f2bf(a.w);
    r[4] = f2bf(b.x); r[5] = f2bf(b.y); r[6] = f2bf(b.z); r[7] = f2bf(b.w);
    return r;
}

__device__ __forceinline__ void gload_lds16(const void* g, void* l) {
    __builtin_amdgcn_global_load_lds(
        (const __attribute__((address_space(1))) unsigned int*)g,
        (__attribute__((address_space(3))) unsigned int*)l,
        16, 0, 0);
}

// ---------------------------------------------------------------------------
// pack_build, regime-separated:
//  blocks 0..10239 (STREAMING, 8-elem units, pure BW):
//      Bm[1024][2048]=bf16([W|U]); Mem=bf16(memory); Qb=bf16(Q);
//      A[:, 0:1024] = bf16(x)
//  blocks 10240..14335 (BUILD, wave-per-row, h only):
//      fp32 logits -> idx;  A[:, 1024:2048] = bf16(h_prev)
// ---------------------------------------------------------------------------
__global__ __launch_bounds__(256) void pack_build_kernel(
        const float* __restrict__ W, const float* __restrict__ U,
        const float* __restrict__ memory, const float* __restrict__ Q,
        const float* __restrict__ x, const float* __restrict__ h_prev,
        const float* __restrict__ M_w, const float* __restrict__ M_b,
        unsigned short* __restrict__ Bm, unsigned short* __restrict__ Mem,
        unsigned short* __restrict__ Qb, unsigned short* __restrict__ A,
        int* __restrict__ idxbuf) {
    if (blockIdx.x < 10240) {
        int u = blockIdx.x * 256 + threadIdx.x;   // 8-elem units
        const float* src;
        unsigned short* dst;
        if (u < 262144) {                          // Bm: 1024 x 2048
            int n  = u >> 8;
            int k8 = (u & 255) << 3;
            src = (k8 < 1024) ? (W + (size_t)n * 1024 + k8)
                              : (U + (size_t)n * 1024 + (k8 - 1024));
            dst = Bm + (size_t)n * K2 + k8;
        } else if (u < 393216) {                   // Mem_bf16: 1M elems
            int f = (u - 262144) << 3;
            src = memory + f;  dst = Mem + f;
        } else if (u < 524288) {                   // Q_bf16: 1M elems
            int f = (u - 393216) << 3;
            src = Q + f;  dst = Qb + f;
        } else {                                   // x -> A[:, 0:1024]
            int e = (u - 524288) << 3;             // flat elem in x
            int row = e >> 10, col = e & 1023;
            src = x + (size_t)row * HIDDEN + col;
            dst = A + (size_t)row * K2 + col;
        }
        float4 a = *reinterpret_cast<const float4*>(src);
        float4 b = *reinterpret_cast<const float4*>(src + 4);
        *reinterpret_cast<u16x8*>(dst) = f2bf8(a, b);
        return;
    }

    // ---- build: one wave per row, h only ----------------------------------
    const int row  = (blockIdx.x - 10240) * 4 + (threadIdx.x >> 6);
    const int lane = threadIdx.x & 63;

    const float* hr = h_prev + (size_t)row * HIDDEN;
    float4 hA0 = *reinterpret_cast<const float4*>(hr + lane * 8);
    float4 hA1 = *reinterpret_cast<const float4*>(hr + lane * 8 + 4);
    float4 hB0 = *reinterpret_cast<const float4*>(hr + 512 + lane * 8);
    float4 hB1 = *reinterpret_cast<const float4*>(hr + 512 + lane * 8 + 4);

    int idx = 0;
#pragma unroll
    for (int j = 0; j < NBITS; ++j) {
        const float* mp = M_w + (size_t)j * HIDDEN;
        float4 mA0 = *reinterpret_cast<const float4*>(mp + lane * 8);
        float4 mA1 = *reinterpret_cast<const float4*>(mp + lane * 8 + 4);
        float4 mB0 = *reinterpret_cast<const float4*>(mp + 512 + lane * 8);
        float4 mB1 = *reinterpret_cast<const float4*>(mp + 512 + lane * 8 + 4);
        float s = (hA0.x * mA0.x + hA0.y * mA0.y + hA0.z * mA0.z + hA0.w * mA0.w)
                + (hA1.x * mA1.x + hA1.y * mA1.y + hA1.z * mA1.z + hA1.w * mA1.w)
                + (hB0.x * mB0.x + hB0.y * mB0.y + hB0.z * mB0.z + hB0.w * mB0.w)
                + (hB1.x * mB1.x + hB1.y * mB1.y + hB1.z * mB1.z + hB1.w * mB1.w);
#pragma unroll
        for (int off = 32; off >= 1; off >>= 1) s += __shfl_xor(s, off, 64);
        if (s + M_b[j] > 0.f) idx |= 1 << (NBITS - 1 - j);
    }
    if (lane == 0) idxbuf[row] = idx;

    unsigned short* arow = A + (size_t)row * K2;
    *reinterpret_cast<u16x8*>(arow + 1024 + lane * 8) = f2bf8(hA0, hA1);
    *reinterpret_cast<u16x8*>(arow + 1536 + lane * 8) = f2bf8(hB0, hB1);
}

// ---------------------------------------------------------------------------
// MQ[1024][1024] f32 = Mem_bf16 @ Qb^T.  Direct (no split-K, no atomics):
// 64 blocks of 128x128, full K loop.  ~2.1 GFLOP, L2-resident inputs.
// ---------------------------------------------------------------------------
__global__ __launch_bounds__(256) void mq_kernel(
        const unsigned short* __restrict__ Mem,
        const unsigned short* __restrict__ Qb,
        float* __restrict__ MQ) {
    __shared__ unsigned short As[128 * 64];
    __shared__ unsigned short Bs[128 * 64];

    const int mb = blockIdx.x >> 3;
    const int nb = blockIdx.x & 7;
    const int t    = threadIdx.x;
    const int lane = t & 63;
    const int w    = t >> 6;
    const int wr   = w >> 1, wc = w & 1;
    const int rr   = lane & 15, rq = lane >> 4;
    const int c8   = (t & 7) * 8;
    const int srow = t >> 3;

    f32x4 acc[4][4] = {};

    for (int kt = 0; kt < 16; ++kt) {
        const int k0 = kt * 64;
#pragma unroll
        for (int i = 0; i < 4; ++i) {
            int r = i * 32 + srow;
            gload_lds16(Mem + (size_t)(mb * 128 + r) * 1024 + k0 + c8, As + i * 2048 + t * 8);
            gload_lds16(Qb  + (size_t)(nb * 128 + r) * 1024 + k0 + c8, Bs + i * 2048 + t * 8);
        }
        __syncthreads();
#pragma unroll
        for (int kk = 0; kk < 2; ++kk) {
            const int krd = kk * 32 + rq * 8;
            bf16x8 af[4], bfv[4];
#pragma unroll
            for (int m = 0; m < 4; ++m)
                af[m] = *reinterpret_cast<const bf16x8*>(As + (wr * 64 + m * 16 + rr) * 64 + krd);
#pragma unroll
            for (int n = 0; n < 4; ++n)
                bfv[n] = *reinterpret_cast<const bf16x8*>(Bs + (wc * 64 + n * 16 + rr) * 64 + krd);
#pragma unroll
            for (int m = 0; m < 4; ++m)
#pragma unroll
                for (int n = 0; n < 4; ++n)
                    acc[m][n] = __builtin_amdgcn_mfma_f32_16x16x32_bf16(
                        af[m], bfv[n], acc[m][n], 0, 0, 0);
        }
        __syncthreads();
    }

#pragma unroll
    for (int m = 0; m < 4; ++m)
#pragma unroll
        for (int n = 0; n < 4; ++n) {
            int gcol = nb * 128 + wc * 64 + n * 16 + rr;
#pragma unroll
            for (int j = 0; j < 4; ++j) {
                int grow = mb * 128 + wr * 64 + m * 16 + rq * 4 + j;
                MQ[(size_t)grow * 1024 + gcol] = acc[m][n][j];
            }
        }
}

// ---------------------------------------------------------------------------
// 256x256-tile GEMM, rotated schedule, one barrier per phase (R7/R8 version).
// ---------------------------------------------------------------------------

__device__ __forceinline__ void stage_g(const unsigned short* __restrict__ src,
                                        int rowbase, int kt, int g,
                                        unsigned short* ldsTile, int t) {
    const int o      = g * 8192 + t * 16;     // byte offset within 32 KB tile
    const int row    = o >> 7;                // 0..255  (128 B per row)
    const int inner  = o & 127;
    const int sinner = inner ^ ((row & 7) << 4);
    const char* gp = reinterpret_cast<const char*>(
                         src + (size_t)(rowbase + row) * K2 + kt * BK) + sinner;
    gload_lds16(gp, reinterpret_cast<char*>(ldsTile) + o);
}

__device__ __forceinline__ bf16x8 ldsfrag(const unsigned short* tile, int row,
                                          int kbyte_x_sw) {
    return *reinterpret_cast<const bf16x8*>(
        reinterpret_cast<const char*>(tile) + row * 128 + kbyte_x_sw);
}

#define PH_BAR()                                                     \
    do {                                                             \
        asm volatile("" ::: "memory");                               \
        __builtin_amdgcn_s_barrier();                                \
        asm volatile("" ::: "memory");                               \
    } while (0)

#define LGKM(N)                                                      \
    do {                                                             \
        asm volatile("s_waitcnt lgkmcnt(" #N ")" ::: "memory");      \
        __builtin_amdgcn_sched_barrier(0);                           \
    } while (0)

#define MFMA_Q(AF, BF, MB, NB)                                                 \
    {                                                                          \
        __builtin_amdgcn_s_setprio(1);                                         \
        _Pragma("unroll") for (int m_ = 0; m_ < 4; ++m_)                       \
        _Pragma("unroll") for (int n_ = 0; n_ < 2; ++n_)                       \
        _Pragma("unroll") for (int kk_ = 0; kk_ < 2; ++kk_)                    \
            acc[(MB) + m_][(NB) + n_] =                                        \
                __builtin_amdgcn_mfma_f32_16x16x32_bf16(                       \
                    AF[m_][kk_], BF[n_][kk_],                                  \
                    acc[(MB) + m_][(NB) + n_], 0, 0, 0);                       \
        __builtin_amdgcn_s_setprio(0);                                         \
    }

__global__ __launch_bounds__(512, 2) void gemm_kernel(
        const unsigned short* __restrict__ A,
        const unsigned short* __restrict__ Bm,
        float* __restrict__ C) {
    __shared__ alignas(16) unsigned short lds[2][2][BM * BK];  // 128 KiB

    const int bid  = blockIdx.x;
    const int wgid = (bid & 7) * 32 + (bid >> 3);
    const int mblk = wgid >> 2;           // 0..63
    const int nblk = wgid & 3;            // 0..3

    const int t    = threadIdx.x;
    const int lane = t & 63;
    const int w    = t >> 6;
    const int wr   = w >> 2;              // 0..1  (M)
    const int wc   = w & 3;               // 0..3  (N)
    const int rr   = lane & 15;
    const int rq   = lane >> 4;
    const int sw   = (rr & 7) << 4;
    const int rqb  = rq * 16;
    const int wrb  = wr * 128;
    const int wcb  = wc * 64;

    const int arow = mblk * BM;
    const int brow = nblk * BN;

    f32x4 acc[8][4] = {};

    {
#pragma unroll
        for (int g = 0; g < 4; ++g) stage_g(A,  arow, 0, g, &lds[0][0][0], t);
#pragma unroll
        for (int g = 0; g < 4; ++g) stage_g(Bm, brow, 0, g, &lds[0][1][0], t);
#pragma unroll
        for (int g = 0; g < 4; ++g) stage_g(Bm, brow, 1, g, &lds[1][1][0], t);
#pragma unroll
        for (int g = 0; g < 4; ++g) stage_g(A,  arow, 1, g, &lds[1][0][0], t);
        asm volatile("s_waitcnt vmcnt(8)" ::: "memory");   // tile0 landed
        asm volatile("" ::: "memory");
        __builtin_amdgcn_s_barrier();
    }

    bf16x8 af  [4][2];   // A rows 0-63 of wave slab
    bf16x8 af2 [4][2];   // A rows 64-127 of wave slab
    bf16x8 bfr01[2][2];  // B cols wcb+0..31
    bf16x8 bfr23[2][2];  // B cols wcb+32..63

#pragma unroll
    for (int m = 0; m < 4; ++m) {
        af[m][0] = ldsfrag(&lds[0][0][0], wrb + m * 16 + rr, (rqb) ^ sw);
        af[m][1] = ldsfrag(&lds[0][0][0], wrb + m * 16 + rr, (64 + rqb) ^ sw);
    }
#pragma unroll
    for (int n = 0; n < 2; ++n) {
        bfr01[n][0] = ldsfrag(&lds[0][1][0], wcb + n * 16 + rr, (rqb) ^ sw);
        bfr01[n][1] = ldsfrag(&lds[0][1][0], wcb + n * 16 + rr, (64 + rqb) ^ sw);
    }

    for (int kt = 0; kt < NT; ++kt) {
        const int c = kt & 1;
        const unsigned short* At  = &lds[c][0][0];
        const unsigned short* Bt  = &lds[c][1][0];
        const unsigned short* nxA = &lds[c ^ 1][0][0];  // tile kt+1
        const unsigned short* nxB = &lds[c ^ 1][1][0];
        unsigned short* curA = &lds[c][0][0];           // tile kt+2 targets
        unsigned short* curB = &lds[c][1][0];
        const bool pf1 = (kt + 1 < NT);
        const bool pf2 = (kt + 2 < NT);

        // -- ph0: read b23(cur) + af2[0] (6); MFMA af x b01 ------------------
        PH_BAR();
#pragma unroll
        for (int n = 0; n < 2; ++n) {
            bfr23[n][0] = ldsfrag(Bt, wcb + 32 + n * 16 + rr, (rqb) ^ sw);
            bfr23[n][1] = ldsfrag(Bt, wcb + 32 + n * 16 + rr, (64 + rqb) ^ sw);
        }
        af2[0][0] = ldsfrag(At, wrb + 64 + rr, (rqb) ^ sw);
        af2[0][1] = ldsfrag(At, wrb + 64 + rr, (64 + rqb) ^ sw);
        LGKM(6);
        MFMA_Q(af, bfr01, 0, 0);

        // -- ph1: read af2[1-3] (6); MFMA af x b23; drain stages -------------
        PH_BAR();
#pragma unroll
        for (int m = 1; m < 4; ++m) {
            af2[m][0] = ldsfrag(At, wrb + 64 + m * 16 + rr, (rqb) ^ sw);
            af2[m][1] = ldsfrag(At, wrb + 64 + m * 16 + rr, (64 + rqb) ^ sw);
        }
        LGKM(8);
        MFMA_Q(af, bfr23, 0, 2);
        __builtin_amdgcn_sched_barrier(0);
        asm volatile("s_waitcnt vmcnt(0)" ::: "memory");  // tile kt+1 landed
        asm volatile("" ::: "memory");

        // -- ph2: stage B(kt+2); read af(kt+1)[0-2] (6); MFMA af2 x b01 ------
        PH_BAR();
        if (pf2) {
            stage_g(Bm, brow, kt + 2, 0, curB, t);
            stage_g(Bm, brow, kt + 2, 1, curB, t);
            stage_g(Bm, brow, kt + 2, 2, curB, t);
            stage_g(Bm, brow, kt + 2, 3, curB, t);
        }
        if (pf1) {
#pragma unroll
            for (int m = 0; m < 3; ++m) {
                af[m][0] = ldsfrag(nxA, wrb + m * 16 + rr, (rqb) ^ sw);
                af[m][1] = ldsfrag(nxA, wrb + m * 16 + rr, (64 + rqb) ^ sw);
            }
            LGKM(6);
        } else {
            LGKM(0);
        }
        MFMA_Q(af2, bfr01, 4, 0);

        // -- ph3: stage A(kt+2); read af[3] + b01(kt+1) (6); MFMA af2 x b23 --
        PH_BAR();
        if (pf2) {
            stage_g(A, arow, kt + 2, 0, curA, t);
            stage_g(A, arow, kt + 2, 1, curA, t);
            stage_g(A, arow, kt + 2, 2, curA, t);
            stage_g(A, arow, kt + 2, 3, curA, t);
        }
        if (pf1) {
            af[3][0] = ldsfrag(nxA, wrb + 48 + rr, (rqb) ^ sw);
            af[3][1] = ldsfrag(nxA, wrb + 48 + rr, (64 + rqb) ^ sw);
#pragma unroll
            for (int n = 0; n < 2; ++n) {
                bfr01[n][0] = ldsfrag(nxB, wcb + n * 16 + rr, (rqb) ^ sw);
                bfr01[n][1] = ldsfrag(nxB, wcb + n * 16 + rr, (64 + rqb) ^ sw);
            }
        }
        MFMA_Q(af2, bfr23, 4, 2);
    }

#pragma unroll
    for (int mi = 0; mi < 8; ++mi) {
#pragma unroll
        for (int n = 0; n < 4; ++n) {
            const int gcol = nblk * BN + wcb + n * 16 + rr;
#pragma unroll
            for (int j = 0; j < 4; ++j) {
                const int grow = mblk * BM + wrb + mi * 16 + rq * 4 + j;
                C[(size_t)grow * HIDDEN + gcol] = acc[mi][n][j];
            }
        }
    }
}

// ---------------------------------------------------------------------------
// In-place: p = C + MQ[idx[row]] + (W_b+U_b+Q_b); LayerNorm; sigmoid.
// ---------------------------------------------------------------------------
__global__ __launch_bounds__(256) void ln_kernel(
        float* __restrict__ C,
        const int* __restrict__ idxbuf,
        const float* __restrict__ MQ,
        const float* __restrict__ W_b, const float* __restrict__ U_b,
        const float* __restrict__ Q_b, const float* __restrict__ ln_g,
        const float* __restrict__ ln_b) {
    const int row = blockIdx.x;
    const int t   = threadIdx.x;
    const int midx = idxbuf[row];
    float4* rowp = reinterpret_cast<float4*>(C + (size_t)row * HIDDEN);
    const float4* mqp = reinterpret_cast<const float4*>(MQ + (size_t)midx * HIDDEN);

    float4 p  = rowp[t];
    float4 mq = mqp[t];
    float4 bw = reinterpret_cast<const float4*>(W_b)[t];
    float4 bu = reinterpret_cast<const float4*>(U_b)[t];
    float4 bq = reinterpret_cast<const float4*>(Q_b)[t];
    p.x += mq.x + bw.x + bu.x + bq.x;
    p.y += mq.y + bw.y + bu.y + bq.y;
    p.z += mq.z + bw.z + bu.z + bq.z;
    p.w += mq.w + bw.w + bu.w + bq.w;

    float s  = p.x + p.y + p.z + p.w;
    float sq = p.x * p.x + p.y * p.y + p.z * p.z + p.w * p.w;
#pragma unroll
    for (int off = 32; off >= 1; off >>= 1) {
        s  += __shfl_xor(s,  off, 64);
        sq += __shfl_xor(sq, off, 64);
    }
    __shared__ float red[8];
    const int lane = t & 63, w = t >> 6;
    if (lane == 0) { red[w] = s; red[4 + w] = sq; }
    __syncthreads();
    const float S    = red[0] + red[1] + red[2] + red[3];
    const float SQ   = red[4] + red[5] + red[6] + red[7];
    const float mean = S * (1.0f / HIDDEN);
    const float var  = SQ * (1.0f / HIDDEN) - mean * mean;
    const float rstd = rsqrtf(var + 1e-5f);

    float4 g = reinterpret_cast<const float4*>(ln_g)[t];
    float4 b = reinterpret_cast<const float4*>(ln_b)[t];
    float4 o;
    o.x = 1.f / (1.f + __expf(-((p.x - mean) * rstd * g.x + b.x)));
    o.y = 1.f / (1.f + __expf(-((p.y - mean) * rstd * g.y + b.y)));
    o.z = 1.f / (1.f + __expf(-((p.z - mean) * rstd * g.z + b.z)));
    o.w = 1.f / (1.f + __expf(-((p.w - mean) * rstd * g.w + b.w)));
    rowp[t] = o;
}

// ---------------------------------------------------------------------------
extern "C" void kernel_launch(void* const* d_in, const int* in_sizes, int n_in,
                              void* d_out, int out_size, void* d_ws, size_t ws_size,
                              hipStream_t stream) {
    const float* x      = (const float*)d_in[0];
    const float* h_prev = (const float*)d_in[1];
    const float* memory = (const float*)d_in[2];
    const float* W_w    = (const float*)d_in[3];
    const float* W_b    = (const float*)d_in[4];
    const float* U_w    = (const float*)d_in[5];
    const float* U_b    = (const float*)d_in[6];
    const float* Q_w    = (const float*)d_in[7];
    const float* Q_b    = (const float*)d_in[8];
    const float* M_w    = (const float*)d_in[9];
    const float* M_b    = (const float*)d_in[10];
    const float* ln_g   = (const float*)d_in[11];
    const float* ln_b   = (const float*)d_in[12];

    // ws layout (bytes):
    char* ws = (char*)d_ws;
    unsigned short* A   = (unsigned short*)(ws);                 // 67,108,864
    unsigned short* Bm  = (unsigned short*)(ws + 67108864);      //  4,194,304
    unsigned short* Mem = (unsigned short*)(ws + 71303168);      //  2,097,152
    unsigned short* Qb  = (unsigned short*)(ws + 73400320);      //  2,097,152
    float*          MQ  = (float*)         (ws + 75497472);      //  4,194,304
    int*            idx = (int*)           (ws + 79691776);      //     65,536
    float* pre = (float*)d_out;

    hipLaunchKernelGGL(pack_build_kernel, dim3(14336), dim3(256), 0, stream,
                       W_w, U_w, memory, Q_w, x, h_prev, M_w, M_b,
                       Bm, Mem, Qb, A, idx);
    hipLaunchKernelGGL(mq_kernel, dim3(64), dim3(256), 0, stream,
                       Mem, Qb, MQ);
    hipLaunchKernelGGL(gemm_kernel, dim3((BATCH / BM) * (HIDDEN / BN)), dim3(512), 0, stream,
                       A, Bm, pre);
    hipLaunchKernelGGL(ln_kernel, dim3(BATCH), dim3(256), 0, stream,
                       pre, idx, MQ, W_b, U_b, Q_b, ln_g, ln_b);
}

// Round 10
// 159.073 us; speedup vs baseline: 1.0908x; 1.0908x over previous
//
#include <hip/hip_runtime.h>

#define BATCH   16384
#define HIDDEN  1024
#define K2      2048     // x | h_prev   (h_mem folded into MQ gather)
#define MEMSZ   1024
#define NBITS   10

#define BM 256
#define BN 256
#define BK 64
#define NT (K2 / BK)     // 32 K-tiles

// streaming geometry: 8-elem units
#define U_BM   262144               // Bm units
#define U_MEM  393216               // + Mem
#define U_QB   524288               // + Qb
#define U_TOT  2621440              // + x   (= 524288 * 5)
#define SGRID  2048                 // streaming blocks
#define SSTRIDE (SGRID * 256)       // 524288 threads

typedef __bf16 bf16x8 __attribute__((ext_vector_type(8)));
typedef float  f32x4  __attribute__((ext_vector_type(4)));
typedef unsigned short u16x8 __attribute__((ext_vector_type(8)));

__device__ __forceinline__ unsigned short f2bf(float f) {
    unsigned int u = __float_as_uint(f);
    u += 0x7FFFu + ((u >> 16) & 1u);   // round-to-nearest-even
    return (unsigned short)(u >> 16);
}

__device__ __forceinline__ u16x8 f2bf8(float4 a, float4 b) {
    u16x8 r;
    r[0] = f2bf(a.x); r[1] = f2bf(a.y); r[2] = f2bf(a.z); r[3] = f2bf(a.w);
    r[4] = f2bf(b.x); r[5] = f2bf(b.y); r[6] = f2bf(b.z); r[7] = f2bf(b.w);
    return r;
}

__device__ __forceinline__ void gload_lds16(const void* g, void* l) {
    __builtin_amdgcn_global_load_lds(
        (const __attribute__((address_space(1))) unsigned int*)g,
        (__attribute__((address_space(3))) unsigned int*)l,
        16, 0, 0);
}

// ---------------------------------------------------------------------------
// pack_build v4:
//  blocks 0..2047   (STREAM): grid-strided, 5 units/thread, all loads issued
//                   before any store (forced ILP via sched_barrier).
//  blocks 2048..4095 (BUILD): M_w staged in LDS once/block; 2 rows/wave;
//                   fp32 logits with 20 interleaved butterfly chains;
//                   A[:,1024:2048] = bf16(h).
// ---------------------------------------------------------------------------
__global__ __launch_bounds__(256) void pack_build_kernel(
        const float* __restrict__ W, const float* __restrict__ U,
        const float* __restrict__ memory, const float* __restrict__ Q,
        const float* __restrict__ x, const float* __restrict__ h_prev,
        const float* __restrict__ M_w, const float* __restrict__ M_b,
        unsigned short* __restrict__ Bm, unsigned short* __restrict__ Mem,
        unsigned short* __restrict__ Qb, unsigned short* __restrict__ A,
        int* __restrict__ idxbuf) {
    if (blockIdx.x < SGRID) {
        const int u0 = blockIdx.x * 256 + threadIdx.x;
        const float* s5[5];
        unsigned short* d5[5];
#pragma unroll
        for (int i = 0; i < 5; ++i) {
            int u = u0 + i * SSTRIDE;
            if (u < U_BM) {                        // Bm: 1024 x 2048
                int n  = u >> 8;
                int k8 = (u & 255) << 3;
                s5[i] = (k8 < 1024) ? (W + (size_t)n * 1024 + k8)
                                    : (U + (size_t)n * 1024 + (k8 - 1024));
                d5[i] = Bm + (size_t)n * K2 + k8;
            } else if (u < U_MEM) {                // Mem_bf16
                int f = (u - U_BM) << 3;
                s5[i] = memory + f;  d5[i] = Mem + f;
            } else if (u < U_QB) {                 // Q_bf16
                int f = (u - U_MEM) << 3;
                s5[i] = Q + f;  d5[i] = Qb + f;
            } else {                               // x -> A[:, 0:1024]
                int e = (u - U_QB) << 3;
                int row = e >> 10, col = e & 1023;
                s5[i] = x + (size_t)row * HIDDEN + col;
                d5[i] = A + (size_t)row * K2 + col;
            }
        }
        float4 va[5], vb[5];
#pragma unroll
        for (int i = 0; i < 5; ++i) {
            va[i] = *reinterpret_cast<const float4*>(s5[i]);
            vb[i] = *reinterpret_cast<const float4*>(s5[i] + 4);
        }
        __builtin_amdgcn_sched_barrier(0);   // all 10 loads issued first
#pragma unroll
        for (int i = 0; i < 5; ++i)
            *reinterpret_cast<u16x8*>(d5[i]) = f2bf8(va[i], vb[i]);
        return;
    }

    // ---- build: M_w in LDS; 2 rows per wave --------------------------------
    __shared__ float mw[NBITS * HIDDEN];   // 40 KB
    for (int i = threadIdx.x; i < (NBITS * HIDDEN) / 4; i += 256)
        reinterpret_cast<float4*>(mw)[i] = reinterpret_cast<const float4*>(M_w)[i];
    __syncthreads();

    const int wv   = threadIdx.x >> 6;
    const int lane = threadIdx.x & 63;
    const int row0 = ((blockIdx.x - SGRID) * 4 + wv) * 2;

    // h for both rows: 8 float4, issued together
    float4 h[2][4];
#pragma unroll
    for (int r = 0; r < 2; ++r) {
        const float* hr = h_prev + (size_t)(row0 + r) * HIDDEN;
        h[r][0] = *reinterpret_cast<const float4*>(hr + lane * 8);
        h[r][1] = *reinterpret_cast<const float4*>(hr + lane * 8 + 4);
        h[r][2] = *reinterpret_cast<const float4*>(hr + 512 + lane * 8);
        h[r][3] = *reinterpret_cast<const float4*>(hr + 512 + lane * 8 + 4);
    }

    // dot partials: M_w slice from LDS, reused for both rows
    float s[2][NBITS];
#pragma unroll
    for (int j = 0; j < NBITS; ++j) {
        const float* mj = mw + j * HIDDEN;
        float4 m0 = *reinterpret_cast<const float4*>(mj + lane * 8);
        float4 m1 = *reinterpret_cast<const float4*>(mj + lane * 8 + 4);
        float4 m2 = *reinterpret_cast<const float4*>(mj + 512 + lane * 8);
        float4 m3 = *reinterpret_cast<const float4*>(mj + 512 + lane * 8 + 4);
#pragma unroll
        for (int r = 0; r < 2; ++r) {
            s[r][j] = (h[r][0].x * m0.x + h[r][0].y * m0.y + h[r][0].z * m0.z + h[r][0].w * m0.w)
                    + (h[r][1].x * m1.x + h[r][1].y * m1.y + h[r][1].z * m1.z + h[r][1].w * m1.w)
                    + (h[r][2].x * m2.x + h[r][2].y * m2.y + h[r][2].z * m2.z + h[r][2].w * m2.w)
                    + (h[r][3].x * m3.x + h[r][3].y * m3.y + h[r][3].z * m3.z + h[r][3].w * m3.w);
        }
    }
    // 20 independent butterfly chains, interleaved per level
#pragma unroll
    for (int off = 32; off >= 1; off >>= 1) {
#pragma unroll
        for (int r = 0; r < 2; ++r)
#pragma unroll
            for (int j = 0; j < NBITS; ++j)
                s[r][j] += __shfl_xor(s[r][j], off, 64);
    }
#pragma unroll
    for (int r = 0; r < 2; ++r) {
        int idx = 0;
#pragma unroll
        for (int j = 0; j < NBITS; ++j)
            if (s[r][j] + M_b[j] > 0.f) idx |= 1 << (NBITS - 1 - j);
        if (lane == 0) idxbuf[row0 + r] = idx;
    }

#pragma unroll
    for (int r = 0; r < 2; ++r) {
        unsigned short* arow = A + (size_t)(row0 + r) * K2;
        *reinterpret_cast<u16x8*>(arow + 1024 + lane * 8) = f2bf8(h[r][0], h[r][1]);
        *reinterpret_cast<u16x8*>(arow + 1536 + lane * 8) = f2bf8(h[r][2], h[r][3]);
    }
}

// ---------------------------------------------------------------------------
// MQ[1024][1024] f32 = Mem_bf16 @ Qb^T.  Direct, 64 blocks of 128x128.
// ---------------------------------------------------------------------------
__global__ __launch_bounds__(256) void mq_kernel(
        const unsigned short* __restrict__ Mem,
        const unsigned short* __restrict__ Qb,
        float* __restrict__ MQ) {
    __shared__ unsigned short As[128 * 64];
    __shared__ unsigned short Bs[128 * 64];

    const int mb = blockIdx.x >> 3;
    const int nb = blockIdx.x & 7;
    const int t    = threadIdx.x;
    const int lane = t & 63;
    const int w    = t >> 6;
    const int wr   = w >> 1, wc = w & 1;
    const int rr   = lane & 15, rq = lane >> 4;
    const int c8   = (t & 7) * 8;
    const int srow = t >> 3;

    f32x4 acc[4][4] = {};

    for (int kt = 0; kt < 16; ++kt) {
        const int k0 = kt * 64;
#pragma unroll
        for (int i = 0; i < 4; ++i) {
            int r = i * 32 + srow;
            gload_lds16(Mem + (size_t)(mb * 128 + r) * 1024 + k0 + c8, As + i * 2048 + t * 8);
            gload_lds16(Qb  + (size_t)(nb * 128 + r) * 1024 + k0 + c8, Bs + i * 2048 + t * 8);
        }
        __syncthreads();
#pragma unroll
        for (int kk = 0; kk < 2; ++kk) {
            const int krd = kk * 32 + rq * 8;
            bf16x8 af[4], bfv[4];
#pragma unroll
            for (int m = 0; m < 4; ++m)
                af[m] = *reinterpret_cast<const bf16x8*>(As + (wr * 64 + m * 16 + rr) * 64 + krd);
#pragma unroll
            for (int n = 0; n < 4; ++n)
                bfv[n] = *reinterpret_cast<const bf16x8*>(Bs + (wc * 64 + n * 16 + rr) * 64 + krd);
#pragma unroll
            for (int m = 0; m < 4; ++m)
#pragma unroll
                for (int n = 0; n < 4; ++n)
                    acc[m][n] = __builtin_amdgcn_mfma_f32_16x16x32_bf16(
                        af[m], bfv[n], acc[m][n], 0, 0, 0);
        }
        __syncthreads();
    }

#pragma unroll
    for (int m = 0; m < 4; ++m)
#pragma unroll
        for (int n = 0; n < 4; ++n) {
            int gcol = nb * 128 + wc * 64 + n * 16 + rr;
#pragma unroll
            for (int j = 0; j < 4; ++j) {
                int grow = mb * 128 + wr * 64 + m * 16 + rq * 4 + j;
                MQ[(size_t)grow * 1024 + gcol] = acc[m][n][j];
            }
        }
}

// ---------------------------------------------------------------------------
// 256x256-tile GEMM, rotated schedule, one barrier per phase (frozen, R8).
// ---------------------------------------------------------------------------

__device__ __forceinline__ void stage_g(const unsigned short* __restrict__ src,
                                        int rowbase, int kt, int g,
                                        unsigned short* ldsTile, int t) {
    const int o      = g * 8192 + t * 16;     // byte offset within 32 KB tile
    const int row    = o >> 7;                // 0..255  (128 B per row)
    const int inner  = o & 127;
    const int sinner = inner ^ ((row & 7) << 4);
    const char* gp = reinterpret_cast<const char*>(
                         src + (size_t)(rowbase + row) * K2 + kt * BK) + sinner;
    gload_lds16(gp, reinterpret_cast<char*>(ldsTile) + o);
}

__device__ __forceinline__ bf16x8 ldsfrag(const unsigned short* tile, int row,
                                          int kbyte_x_sw) {
    return *reinterpret_cast<const bf16x8*>(
        reinterpret_cast<const char*>(tile) + row * 128 + kbyte_x_sw);
}

#define PH_BAR()                                                     \
    do {                                                             \
        asm volatile("" ::: "memory");                               \
        __builtin_amdgcn_s_barrier();                                \
        asm volatile("" ::: "memory");                               \
    } while (0)

#define LGKM(N)                                                      \
    do {                                                             \
        asm volatile("s_waitcnt lgkmcnt(" #N ")" ::: "memory");      \
        __builtin_amdgcn_sched_barrier(0);                           \
    } while (0)

#define MFMA_Q(AF, BF, MB, NB)                                                 \
    {                                                                          \
        __builtin_amdgcn_s_setprio(1);                                         \
        _Pragma("unroll") for (int m_ = 0; m_ < 4; ++m_)                       \
        _Pragma("unroll") for (int n_ = 0; n_ < 2; ++n_)                       \
        _Pragma("unroll") for (int kk_ = 0; kk_ < 2; ++kk_)                    \
            acc[(MB) + m_][(NB) + n_] =                                        \
                __builtin_amdgcn_mfma_f32_16x16x32_bf16(                       \
                    AF[m_][kk_], BF[n_][kk_],                                  \
                    acc[(MB) + m_][(NB) + n_], 0, 0, 0);                       \
        __builtin_amdgcn_s_setprio(0);                                         \
    }

__global__ __launch_bounds__(512, 2) void gemm_kernel(
        const unsigned short* __restrict__ A,
        const unsigned short* __restrict__ Bm,
        float* __restrict__ C) {
    __shared__ alignas(16) unsigned short lds[2][2][BM * BK];  // 128 KiB

    const int bid  = blockIdx.x;
    const int wgid = (bid & 7) * 32 + (bid >> 3);
    const int mblk = wgid >> 2;           // 0..63
    const int nblk = wgid & 3;            // 0..3

    const int t    = threadIdx.x;
    const int lane = t & 63;
    const int w    = t >> 6;
    const int wr   = w >> 2;              // 0..1  (M)
    const int wc   = w & 3;               // 0..3  (N)
    const int rr   = lane & 15;
    const int rq   = lane >> 4;
    const int sw   = (rr & 7) << 4;
    const int rqb  = rq * 16;
    const int wrb  = wr * 128;
    const int wcb  = wc * 64;

    const int arow = mblk * BM;
    const int brow = nblk * BN;

    f32x4 acc[8][4] = {};

    {
#pragma unroll
        for (int g = 0; g < 4; ++g) stage_g(A,  arow, 0, g, &lds[0][0][0], t);
#pragma unroll
        for (int g = 0; g < 4; ++g) stage_g(Bm, brow, 0, g, &lds[0][1][0], t);
#pragma unroll
        for (int g = 0; g < 4; ++g) stage_g(Bm, brow, 1, g, &lds[1][1][0], t);
#pragma unroll
        for (int g = 0; g < 4; ++g) stage_g(A,  arow, 1, g, &lds[1][0][0], t);
        asm volatile("s_waitcnt vmcnt(8)" ::: "memory");   // tile0 landed
        asm volatile("" ::: "memory");
        __builtin_amdgcn_s_barrier();
    }

    bf16x8 af  [4][2];   // A rows 0-63 of wave slab
    bf16x8 af2 [4][2];   // A rows 64-127 of wave slab
    bf16x8 bfr01[2][2];  // B cols wcb+0..31
    bf16x8 bfr23[2][2];  // B cols wcb+32..63

#pragma unroll
    for (int m = 0; m < 4; ++m) {
        af[m][0] = ldsfrag(&lds[0][0][0], wrb + m * 16 + rr, (rqb) ^ sw);
        af[m][1] = ldsfrag(&lds[0][0][0], wrb + m * 16 + rr, (64 + rqb) ^ sw);
    }
#pragma unroll
    for (int n = 0; n < 2; ++n) {
        bfr01[n][0] = ldsfrag(&lds[0][1][0], wcb + n * 16 + rr, (rqb) ^ sw);
        bfr01[n][1] = ldsfrag(&lds[0][1][0], wcb + n * 16 + rr, (64 + rqb) ^ sw);
    }

    for (int kt = 0; kt < NT; ++kt) {
        const int c = kt & 1;
        const unsigned short* At  = &lds[c][0][0];
        const unsigned short* Bt  = &lds[c][1][0];
        const unsigned short* nxA = &lds[c ^ 1][0][0];  // tile kt+1
        const unsigned short* nxB = &lds[c ^ 1][1][0];
        unsigned short* curA = &lds[c][0][0];           // tile kt+2 targets
        unsigned short* curB = &lds[c][1][0];
        const bool pf1 = (kt + 1 < NT);
        const bool pf2 = (kt + 2 < NT);

        // -- ph0: read b23(cur) + af2[0] (6); MFMA af x b01 ------------------
        PH_BAR();
#pragma unroll
        for (int n = 0; n < 2; ++n) {
            bfr23[n][0] = ldsfrag(Bt, wcb + 32 + n * 16 + rr, (rqb) ^ sw);
            bfr23[n][1] = ldsfrag(Bt, wcb + 32 + n * 16 + rr, (64 + rqb) ^ sw);
        }
        af2[0][0] = ldsfrag(At, wrb + 64 + rr, (rqb) ^ sw);
        af2[0][1] = ldsfrag(At, wrb + 64 + rr, (64 + rqb) ^ sw);
        LGKM(6);
        MFMA_Q(af, bfr01, 0, 0);

        // -- ph1: read af2[1-3] (6); MFMA af x b23; drain stages -------------
        PH_BAR();
#pragma unroll
        for (int m = 1; m < 4; ++m) {
            af2[m][0] = ldsfrag(At, wrb + 64 + m * 16 + rr, (rqb) ^ sw);
            af2[m][1] = ldsfrag(At, wrb + 64 + m * 16 + rr, (64 + rqb) ^ sw);
        }
        LGKM(8);
        MFMA_Q(af, bfr23, 0, 2);
        __builtin_amdgcn_sched_barrier(0);
        asm volatile("s_waitcnt vmcnt(0)" ::: "memory");  // tile kt+1 landed
        asm volatile("" ::: "memory");

        // -- ph2: stage B(kt+2); read af(kt+1)[0-2] (6); MFMA af2 x b01 ------
        PH_BAR();
        if (pf2) {
            stage_g(Bm, brow, kt + 2, 0, curB, t);
            stage_g(Bm, brow, kt + 2, 1, curB, t);
            stage_g(Bm, brow, kt + 2, 2, curB, t);
            stage_g(Bm, brow, kt + 2, 3, curB, t);
        }
        if (pf1) {
#pragma unroll
            for (int m = 0; m < 3; ++m) {
                af[m][0] = ldsfrag(nxA, wrb + m * 16 + rr, (rqb) ^ sw);
                af[m][1] = ldsfrag(nxA, wrb + m * 16 + rr, (64 + rqb) ^ sw);
            }
            LGKM(6);
        } else {
            LGKM(0);
        }
        MFMA_Q(af2, bfr01, 4, 0);

        // -- ph3: stage A(kt+2); read af[3] + b01(kt+1) (6); MFMA af2 x b23 --
        PH_BAR();
        if (pf2) {
            stage_g(A, arow, kt + 2, 0, curA, t);
            stage_g(A, arow, kt + 2, 1, curA, t);
            stage_g(A, arow, kt + 2, 2, curA, t);
            stage_g(A, arow, kt + 2, 3, curA, t);
        }
        if (pf1) {
            af[3][0] = ldsfrag(nxA, wrb + 48 + rr, (rqb) ^ sw);
            af[3][1] = ldsfrag(nxA, wrb + 48 + rr, (64 + rqb) ^ sw);
#pragma unroll
            for (int n = 0; n < 2; ++n) {
                bfr01[n][0] = ldsfrag(nxB, wcb + n * 16 + rr, (rqb) ^ sw);
                bfr01[n][1] = ldsfrag(nxB, wcb + n * 16 + rr, (64 + rqb) ^ sw);
            }
        }
        MFMA_Q(af2, bfr23, 4, 2);
    }

#pragma unroll
    for (int mi = 0; mi < 8; ++mi) {
#pragma unroll
        for (int n = 0; n < 4; ++n) {
            const int gcol = nblk * BN + wcb + n * 16 + rr;
#pragma unroll
            for (int j = 0; j < 4; ++j) {
                const int grow = mblk * BM + wrb + mi * 16 + rq * 4 + j;
                C[(size_t)grow * HIDDEN + gcol] = acc[mi][n][j];
            }
        }
    }
}

// ---------------------------------------------------------------------------
// In-place: p = C + MQ[idx[row]] + (W_b+U_b+Q_b); LayerNorm; sigmoid.
// ---------------------------------------------------------------------------
__global__ __launch_bounds__(256) void ln_kernel(
        float* __restrict__ C,
        const int* __restrict__ idxbuf,
        const float* __restrict__ MQ,
        const float* __restrict__ W_b, const float* __restrict__ U_b,
        const float* __restrict__ Q_b, const float* __restrict__ ln_g,
        const float* __restrict__ ln_b) {
    const int row = blockIdx.x;
    const int t   = threadIdx.x;
    const int midx = idxbuf[row];
    float4* rowp = reinterpret_cast<float4*>(C + (size_t)row * HIDDEN);
    const float4* mqp = reinterpret_cast<const float4*>(MQ + (size_t)midx * HIDDEN);

    float4 p  = rowp[t];
    float4 mq = mqp[t];
    float4 bw = reinterpret_cast<const float4*>(W_b)[t];
    float4 bu = reinterpret_cast<const float4*>(U_b)[t];
    float4 bq = reinterpret_cast<const float4*>(Q_b)[t];
    p.x += mq.x + bw.x + bu.x + bq.x;
    p.y += mq.y + bw.y + bu.y + bq.y;
    p.z += mq.z + bw.z + bu.z + bq.z;
    p.w += mq.w + bw.w + bu.w + bq.w;

    float s  = p.x + p.y + p.z + p.w;
    float sq = p.x * p.x + p.y * p.y + p.z * p.z + p.w * p.w;
#pragma unroll
    for (int off = 32; off >= 1; off >>= 1) {
        s  += __shfl_xor(s,  off, 64);
        sq += __shfl_xor(sq, off, 64);
    }
    __shared__ float red[8];
    const int lane = t & 63, w = t >> 6;
    if (lane == 0) { red[w] = s; red[4 + w] = sq; }
    __syncthreads();
    const float S    = red[0] + red[1] + red[2] + red[3];
    const float SQ   = red[4] + red[5] + red[6] + red[7];
    const float mean = S * (1.0f / HIDDEN);
    const float var  = SQ * (1.0f / HIDDEN) - mean * mean;
    const float rstd = rsqrtf(var + 1e-5f);

    float4 g = reinterpret_cast<const float4*>(ln_g)[t];
    float4 b = reinterpret_cast<const float4*>(ln_b)[t];
    float4 o;
    o.x = 1.f / (1.f + __expf(-((p.x - mean) * rstd * g.x + b.x)));
    o.y = 1.f / (1.f + __expf(-((p.y - mean) * rstd * g.y + b.y)));
    o.z = 1.f / (1.f + __expf(-((p.z - mean) * rstd * g.z + b.z)));
    o.w = 1.f / (1.f + __expf(-((p.w - mean) * rstd * g.w + b.w)));
    rowp[t] = o;
}

// ---------------------------------------------------------------------------
extern "C" void kernel_launch(void* const* d_in, const int* in_sizes, int n_in,
                              void* d_out, int out_size, void* d_ws, size_t ws_size,
                              hipStream_t stream) {
    const float* x      = (const float*)d_in[0];
    const float* h_prev = (const float*)d_in[1];
    const float* memory = (const float*)d_in[2];
    const float* W_w    = (const float*)d_in[3];
    const float* W_b    = (const float*)d_in[4];
    const float* U_w    = (const float*)d_in[5];
    const float* U_b    = (const float*)d_in[6];
    const float* Q_w    = (const float*)d_in[7];
    const float* Q_b    = (const float*)d_in[8];
    const float* M_w    = (const float*)d_in[9];
    const float* M_b    = (const float*)d_in[10];
    const float* ln_g   = (const float*)d_in[11];
    const float* ln_b   = (const float*)d_in[12];

    // ws layout (bytes):
    char* ws = (char*)d_ws;
    unsigned short* A   = (unsigned short*)(ws);                 // 67,108,864
    unsigned short* Bm  = (unsigned short*)(ws + 67108864);      //  4,194,304
    unsigned short* Mem = (unsigned short*)(ws + 71303168);      //  2,097,152
    unsigned short* Qb  = (unsigned short*)(ws + 73400320);      //  2,097,152
    float*          MQ  = (float*)         (ws + 75497472);      //  4,194,304
    int*            idx = (int*)           (ws + 79691776);      //     65,536
    float* pre = (float*)d_out;

    hipLaunchKernelGGL(pack_build_kernel, dim3(SGRID + 2048), dim3(256), 0, stream,
                       W_w, U_w, memory, Q_w, x, h_prev, M_w, M_b,
                       Bm, Mem, Qb, A, idx);
    hipLaunchKernelGGL(mq_kernel, dim3(64), dim3(256), 0, stream,
                       Mem, Qb, MQ);
    hipLaunchKernelGGL(gemm_kernel, dim3((BATCH / BM) * (HIDDEN / BN)), dim3(512), 0, stream,
                       A, Bm, pre);
    hipLaunchKernelGGL(ln_kernel, dim3(BATCH), dim3(256), 0, stream,
                       pre, idx, MQ, W_b, U_b, Q_b, ln_g, ln_b);
}